// Round 2
// baseline (5326.628 us; speedup 1.0000x reference)
//
#include <hip/hip_runtime.h>

// SNN forward: x[B,1,28,28] -> [T=28,B,28] -> Linear(28,32) -> IF
// -> Linear(32,10) -> IF -> mean spikes over T.
//
// Round-2 structure: layer-1 computed in OUTER-PRODUCT form straight from
// global memory (L1-served broadcasts), removing all layer-1 LDS traffic
// (round-1 was LDS-pipe-bound: 196 ds_read_b128 + 224 ds_read_b32 per wave
// == the entire 194 us). Lane (s,o) holds acc[t=0..27] in VGPRs; the i-loop
// reads x[s][i][t0..t3] as float4 (contiguous in native [b][i][t] layout).
// Per-t fmaf chain over ascending i is bit-identical to round-1 -> spikes
// identical -> absmax 0.
//
// IF scan + layer-2 nibble-LUT (5 KB LDS) unchanged; LDS pipe now only
// carries 224 b32/wave. No staging scatter -> bank conflicts gone.

#define SPB     8
#define THREADS 256

__global__ __launch_bounds__(THREADS, 4) void snn_if_kernel(
    const float* __restrict__ x,    // [B][28][28]  (b, i, t) t fastest
    const float* __restrict__ W1,   // [32][28]
    const float* __restrict__ b1,   // [32]
    const float* __restrict__ W2,   // [10][32]
    const float* __restrict__ b2,   // [10]
    float* __restrict__ out,        // [B][10]
    int B)
{
    __shared__ float Tbl[1280];     // [k<8][nib<16][o2<10]

    const int tid  = threadIdx.x;
    const int o    = tid & 31;      // layer-1 neuron; also o2 for layer 2
    const int sl   = tid >> 5;      // local sample 0..7
    const int samp = blockIdx.x * SPB + sl;
    const int ok   = (samp < B);

    // ---- build layer-2 nibble tables: Tbl[(k*16+n)*10+o2] = sum_{j in n} W2[o2][4k+j]
    for (int e = tid; e < 1280; e += THREADS) {
        int o2 = e % 10;
        int tn = e / 10;            // 0..127
        int n  = tn & 15;
        int k  = tn >> 4;
        float v = 0.f;
        if (n & 1) v += W2[o2 * 32 + 4 * k + 0];
        if (n & 2) v += W2[o2 * 32 + 4 * k + 1];
        if (n & 4) v += W2[o2 * 32 + 4 * k + 2];
        if (n & 8) v += W2[o2 * 32 + 4 * k + 3];
        Tbl[e] = v;
    }

    // ---- per-lane layer-1 weights in registers ----
    float w1r[28];
    {
        const float4* w4 = (const float4*)(W1 + o * 28);  // 112 B, 16B-aligned
        #pragma unroll
        for (int q = 0; q < 7; ++q) {
            float4 v = w4[q];
            w1r[4 * q + 0] = v.x; w1r[4 * q + 1] = v.y;
            w1r[4 * q + 2] = v.z; w1r[4 * q + 3] = v.w;
        }
    }
    const float b1o = b1[o];
    const float b2o = (o < 10) ? b2[o] : 0.f;

    __syncthreads();

    // ---- layer-1 outer product: acc[t] += W1[o][i] * x[s][i][t], i ascending
    float acc[28];
    #pragma unroll
    for (int t = 0; t < 28; ++t) acc[t] = 0.f;

    const float* xs = x + (size_t)(ok ? samp : 0) * 784;  // sample's 784 floats
    #pragma unroll
    for (int i = 0; i < 28; ++i) {
        const float4* xr = (const float4*)(xs + i * 28);  // row i: 7 aligned float4
        float4 a0 = xr[0], a1 = xr[1], a2 = xr[2], a3 = xr[3];
        float4 a4 = xr[4], a5 = xr[5], a6 = xr[6];
        const float w = w1r[i];
        acc[ 0] = fmaf(w, a0.x, acc[ 0]);
        acc[ 1] = fmaf(w, a0.y, acc[ 1]);
        acc[ 2] = fmaf(w, a0.z, acc[ 2]);
        acc[ 3] = fmaf(w, a0.w, acc[ 3]);
        acc[ 4] = fmaf(w, a1.x, acc[ 4]);
        acc[ 5] = fmaf(w, a1.y, acc[ 5]);
        acc[ 6] = fmaf(w, a1.z, acc[ 6]);
        acc[ 7] = fmaf(w, a1.w, acc[ 7]);
        acc[ 8] = fmaf(w, a2.x, acc[ 8]);
        acc[ 9] = fmaf(w, a2.y, acc[ 9]);
        acc[10] = fmaf(w, a2.z, acc[10]);
        acc[11] = fmaf(w, a2.w, acc[11]);
        acc[12] = fmaf(w, a3.x, acc[12]);
        acc[13] = fmaf(w, a3.y, acc[13]);
        acc[14] = fmaf(w, a3.z, acc[14]);
        acc[15] = fmaf(w, a3.w, acc[15]);
        acc[16] = fmaf(w, a4.x, acc[16]);
        acc[17] = fmaf(w, a4.y, acc[17]);
        acc[18] = fmaf(w, a4.z, acc[18]);
        acc[19] = fmaf(w, a4.w, acc[19]);
        acc[20] = fmaf(w, a5.x, acc[20]);
        acc[21] = fmaf(w, a5.y, acc[21]);
        acc[22] = fmaf(w, a5.z, acc[22]);
        acc[23] = fmaf(w, a5.w, acc[23]);
        acc[24] = fmaf(w, a6.x, acc[24]);
        acc[25] = fmaf(w, a6.y, acc[25]);
        acc[26] = fmaf(w, a6.z, acc[26]);
        acc[27] = fmaf(w, a6.w, acc[27]);
    }

    // ---- sequential IF scan over t (layer 1) fused with layer 2 ----
    float v1 = 0.f, v2 = 0.f, cnt = 0.f;

    #pragma unroll
    for (int t = 0; t < 28; ++t) {
        v1 += acc[t] + b1o;                    // v += h1   (same op order as r1)
        bool sp = (v1 >= 1.0f);                // spike = H(v - 1)
        unsigned long long bal = __ballot(sp); // bit L = lane L's spike
        if (sp) v1 = 0.0f;                     // hard reset
        unsigned m = (unsigned)(bal >> (tid & 32)); // my half-wave's 32 bits

        if (o < 10) {
            float acc2 = 0.f;
            #pragma unroll
            for (int k = 0; k < 8; ++k) {
                unsigned nib = (m >> (4 * k)) & 15u;
                acc2 += Tbl[k * 160 + nib * 10 + o];
            }
            v2 += acc2 + b2o;                  // v += h2
            if (v2 >= 1.0f) { cnt += 1.0f; v2 = 0.0f; }
        }
    }

    if (o < 10 && ok) {
        out[(size_t)samp * 10 + o] = cnt / 28.0f;
    }
}

extern "C" void kernel_launch(void* const* d_in, const int* in_sizes, int n_in,
                              void* d_out, int out_size, void* d_ws, size_t ws_size,
                              hipStream_t stream) {
    const float* x  = (const float*)d_in[0];
    const float* W1 = (const float*)d_in[1];
    const float* b1 = (const float*)d_in[2];
    const float* W2 = (const float*)d_in[3];
    const float* b2 = (const float*)d_in[4];
    float* out = (float*)d_out;

    int B = in_sizes[0] / 784;           // 65536
    int grid = (B + SPB - 1) / SPB;      // 8192
    snn_if_kernel<<<grid, THREADS, 0, stream>>>(x, W1, b1, W2, b2, out, B);
}

// Round 3
// 3786.367 us; speedup vs baseline: 1.4068x; 1.4068x over previous
//
#include <hip/hip_runtime.h>

// SNN forward: x[B,1,28,28] -> [T=28,B,28] -> Linear(28,32) -> IF
// -> Linear(32,10) -> IF -> mean spikes over T.
//
// Round-3:
//  * Layer-1 outer-product straight from global (L1 broadcast within the
//    32-lane sample group), t-chunked 16+12 so acc[] stays <=16 VGPRs ->
//    no spills (round-2 failure: full 28-acc unroll spilled to scratch,
//    17 GB of scratch traffic). All 196 loads use immediate offsets off
//    one per-sample base. Ascending-i fmaf chain per t is bit-identical
//    to rounds 1/2.
//  * Layer-2 via byte-pair LUT P[4][256][10] (40 KB LDS): 4 ds_read_b32
//    per t instead of 8 (halves the LDS-pipe load that dominated r1).
//    P[g][b][o2] = fl(T4[2g][b&15] + T4[2g+1][b>>4]); acc2 = ((P0+P1)+P2)+P3.
//  * Grid-strided: 768 blocks (3/CU, the 46 KB LDS limit), 8 samples per
//    block-iteration -> table build amortized over ~88 samples.

#define THREADS 256
#define SPB     8     // samples per block-iteration (2/wave x 4 waves)
#define GRID    768   // 3 blocks/CU x 256 CU

template<int NT>
__device__ __forceinline__ void run_chunk(
    const float* __restrict__ xs,   // sample base, pre-offset by T0 floats
    const float* __restrict__ w1r,  // 28 layer-1 weights (registers)
    const float* __restrict__ P,    // byte-pair LUT in LDS
    int tid, int o, float b1o, float b2o,
    float& v1, float& v2, float& cnt)
{
    float acc[NT];
    #pragma unroll
    for (int t = 0; t < NT; ++t) acc[t] = 0.f;

    // acc[t] += W1[o][i] * x[s][i][T0+t], i ascending (bit-exact vs r1/r2)
    #pragma unroll
    for (int i = 0; i < 28; ++i) {
        const float w = w1r[i];
        const float4* row = (const float4*)(xs + i * 28); // 16B-aligned
        #pragma unroll
        for (int q = 0; q < NT / 4; ++q) {
            float4 a = row[q];
            acc[4*q+0] = fmaf(w, a.x, acc[4*q+0]);
            acc[4*q+1] = fmaf(w, a.y, acc[4*q+1]);
            acc[4*q+2] = fmaf(w, a.z, acc[4*q+2]);
            acc[4*q+3] = fmaf(w, a.w, acc[4*q+3]);
        }
    }

    // sequential IF scan fused with layer 2
    #pragma unroll
    for (int t = 0; t < NT; ++t) {
        v1 += acc[t] + b1o;                     // v += h1 (same order as r1)
        bool sp = (v1 >= 1.0f);                 // spike = H(v - 1)
        unsigned long long bal = __ballot(sp);
        if (sp) v1 = 0.0f;                      // hard reset
        unsigned m = (unsigned)(bal >> (tid & 32)); // my half-wave's 32 bits

        if (o < 10) {
            unsigned b0 =  m         & 255u;
            unsigned b1 = (m >> 8)   & 255u;
            unsigned b2 = (m >> 16)  & 255u;
            unsigned b3 =  m >> 24;
            float a2 =  P[(        b0) * 10 + o];
            a2      +=  P[( 256u + b1) * 10 + o];
            a2      +=  P[( 512u + b2) * 10 + o];
            a2      +=  P[( 768u + b3) * 10 + o];
            v2 += a2 + b2o;                     // v += h2
            if (v2 >= 1.0f) { cnt += 1.0f; v2 = 0.0f; }
        }
    }
}

__global__ __launch_bounds__(THREADS, 3) void snn_if_kernel(
    const float* __restrict__ x,    // [B][28][28]  (b, i, t) t fastest
    const float* __restrict__ W1,   // [32][28]
    const float* __restrict__ b1,   // [32]
    const float* __restrict__ W2,   // [10][32]
    const float* __restrict__ b2,   // [10]
    float* __restrict__ out,        // [B][10]
    int B, int nIter)
{
    __shared__ float T4[1280];      // nibble tables [k<8][nib<16][o2<10]
    __shared__ float P[10240];      // byte-pair tables [g<4][byte<256][o2<10]

    const int tid = threadIdx.x;
    const int o   = tid & 31;       // layer-1 neuron; o<10 -> layer-2 neuron
    const int sl  = tid >> 5;       // local sample slot 0..7

    // ---- nibble tables (exact r1 arithmetic) ----
    for (int e = tid; e < 1280; e += THREADS) {
        int o2 = e % 10;
        int tn = e / 10;            // 0..127
        int n  = tn & 15;
        int k  = tn >> 4;
        float v = 0.f;
        if (n & 1) v += W2[o2 * 32 + 4 * k + 0];
        if (n & 2) v += W2[o2 * 32 + 4 * k + 1];
        if (n & 4) v += W2[o2 * 32 + 4 * k + 2];
        if (n & 8) v += W2[o2 * 32 + 4 * k + 3];
        T4[e] = v;
    }

    // ---- per-lane layer-1 weights ----
    float w1r[28];
    {
        const float4* w4 = (const float4*)(W1 + o * 28);  // 112 B stride, aligned
        #pragma unroll
        for (int q = 0; q < 7; ++q) {
            float4 v = w4[q];
            w1r[4*q+0] = v.x; w1r[4*q+1] = v.y;
            w1r[4*q+2] = v.z; w1r[4*q+3] = v.w;
        }
    }
    const float b1o = b1[o];
    const float b2o = (o < 10) ? b2[o] : 0.f;

    __syncthreads();

    // ---- byte-pair tables: P[(g*256+b)*10+o2] = T4[2g][b&15] + T4[2g+1][b>>4]
    for (int e = tid; e < 10240; e += THREADS) {
        int o2 = e % 10;
        int r  = e / 10;            // 0..1023
        int bb = r & 255;
        int g  = r >> 8;
        P[e] = T4[((2*g  ) * 16 + (bb & 15)) * 10 + o2]
             + T4[((2*g+1) * 16 + (bb >> 4)) * 10 + o2];
    }
    __syncthreads();

    // ---- grid-strided main loop: 8 samples per block-iteration ----
    for (int it = 0; it < nIter; ++it) {
        int samp = (blockIdx.x * nIter + it) * SPB + sl;
        bool ok  = (samp < B);
        const float* xs = x + (size_t)(ok ? samp : 0) * 784;

        float v1 = 0.f, v2 = 0.f, cnt = 0.f;
        run_chunk<16>(xs,      w1r, P, tid, o, b1o, b2o, v1, v2, cnt);
        run_chunk<12>(xs + 16, w1r, P, tid, o, b1o, b2o, v1, v2, cnt);

        if (o < 10 && ok) {
            out[(size_t)samp * 10 + o] = cnt / 28.0f;   // same div as r1
        }
    }
}

extern "C" void kernel_launch(void* const* d_in, const int* in_sizes, int n_in,
                              void* d_out, int out_size, void* d_ws, size_t ws_size,
                              hipStream_t stream) {
    const float* x  = (const float*)d_in[0];
    const float* W1 = (const float*)d_in[1];
    const float* b1 = (const float*)d_in[2];
    const float* W2 = (const float*)d_in[3];
    const float* b2 = (const float*)d_in[4];
    float* out = (float*)d_out;

    int B = in_sizes[0] / 784;                        // 65536
    int nIter = (B + GRID * SPB - 1) / (GRID * SPB);  // 11 for B=65536
    snn_if_kernel<<<GRID, THREADS, 0, stream>>>(x, W1, b1, W2, b2, out, B, nIter);
}

// Round 4
// 410.021 us; speedup vs baseline: 12.9911x; 9.2346x over previous
//
#include <hip/hip_runtime.h>

// SNN forward: x[B,1,28,28] -> [T=28,B,28] -> Linear(28,32) -> IF
// -> Linear(32,10) -> IF -> mean spikes over T.
//
// Round-4: spill-proof outer-product.
//  * 16 lanes per sample, 2 neurons per lane (o=p and o=p+16): 4 samples
//    per wave -> halves all per-sample wave-instruction counts vs r1/r3.
//  * Layer-1 streams x rows from global (L1 broadcast within each 16-lane
//    group) in a ROLLED (#pragma unroll 1), manually software-pipelined
//    i-loop (step 2, ping-pong c[7]/n[7] float4 buffers). All register
//    arrays are constant-indexed (inner q-loops unrolled) -> SROA, no
//    scratch. Round-2/3 failure was full-unroll load hoisting -> spills
//    (4.4 GB scratch writes); this bounds loads-in-flight to 14.
//  * W1 lives in LDS padded [32][29] (29 coprime 32 -> conflict-free
//    broadcast reads), not per-lane registers (dynamic-indexed local
//    array was scratch-allocated in r3).
//  * Layer-2 byte-pair LUT P[4][256][10] (40 KB LDS): 4 ds_read_b32 per t
//    per wave now serves 4 samples (lanes p<10 of each group).
//  * Bit-exact FP op order vs r1/r3 (absmax 0.0): ascending-i fmaf chain,
//    v1 += acc[t]+b1, LUT sum ((P0+P1)+P2)+P3, cnt/28.
// LDS ~50 KB -> 3 blocks/CU; ~140 VGPR @ __launch_bounds__(256,3).

#define THREADS 256
#define GRID    768   // 3 blocks/CU x 256 CU
#define SPB     16    // samples per block-iteration (4/wave x 4 waves)

__global__ __launch_bounds__(THREADS, 3) void snn_if_kernel(
    const float* __restrict__ x,    // [B][28][28]  (b, i, t) t fastest
    const float* __restrict__ W1,   // [32][28]
    const float* __restrict__ b1,   // [32]
    const float* __restrict__ W2,   // [10][32]
    const float* __restrict__ b2,   // [10]
    float* __restrict__ out,        // [B][10]
    int B, int nIter)
{
    __shared__ float Ws[32 * 29];   // W1 padded stride 29 (conflict-free)
    __shared__ float T4[1280];      // nibble tables [k<8][nib<16][o2<10]
    __shared__ float P[10240];      // byte-pair tables [g<4][byte<256][o2<10]

    const int tid = threadIdx.x;
    const int p   = tid & 15;         // lane owns neurons o=p and o=p+16
    const int g16 = (tid & 63) >> 4;  // 16-lane sample group within wave
    const int sl  = tid >> 4;         // sample slot within block 0..15

    // ---- W1 -> LDS (padded) ----
    for (int e = tid; e < 32 * 28; e += THREADS) {
        int o = e / 28, i = e - o * 28;
        Ws[o * 29 + i] = W1[e];
    }
    // ---- nibble tables (exact r1 arithmetic) ----
    for (int e = tid; e < 1280; e += THREADS) {
        int o2 = e % 10;
        int tn = e / 10;
        int nb = tn & 15, k = tn >> 4;
        float v = 0.f;
        if (nb & 1) v += W2[o2 * 32 + 4 * k + 0];
        if (nb & 2) v += W2[o2 * 32 + 4 * k + 1];
        if (nb & 4) v += W2[o2 * 32 + 4 * k + 2];
        if (nb & 8) v += W2[o2 * 32 + 4 * k + 3];
        T4[e] = v;
    }
    __syncthreads();
    // ---- byte-pair tables: P[(g*256+b)*10+o2] = T4[2g][b&15] + T4[2g+1][b>>4]
    for (int e = tid; e < 10240; e += THREADS) {
        int o2 = e % 10;
        int r  = e / 10;
        int bb = r & 255, g = r >> 8;
        P[e] = T4[((2 * g    ) * 16 + (bb & 15)) * 10 + o2]
             + T4[((2 * g + 1) * 16 + (bb >> 4)) * 10 + o2];
    }

    const float b1a = b1[p];
    const float b1b = b1[p + 16];
    const float b2o = (p < 10) ? b2[p] : 0.f;
    __syncthreads();

    for (int it = 0; it < nIter; ++it) {
        int samp = (blockIdx.x * nIter + it) * SPB + sl;
        bool ok  = (samp < B);
        const float* xs = x + (size_t)(ok ? samp : 0) * 784;

        float accA[28], accB[28];
        #pragma unroll
        for (int t = 0; t < 28; ++t) { accA[t] = 0.f; accB[t] = 0.f; }

        float4 c[7], n[7];
        {
            const float4* r0 = (const float4*)xs;       // row 0
            #pragma unroll
            for (int q = 0; q < 7; ++q) c[q] = r0[q];
        }

        // acc[t] += W1[o][i] * x[i][t], i ascending; ping-pong 1-row lookahead
        #pragma unroll 1
        for (int i = 0; i < 28; i += 2) {
            const float4* rn = (const float4*)(xs + (i + 1) * 28);  // row i+1
            #pragma unroll
            for (int q = 0; q < 7; ++q) n[q] = rn[q];
            float wA = Ws[p * 29 + i];
            float wB = Ws[(p + 16) * 29 + i];
            #pragma unroll
            for (int q = 0; q < 7; ++q) {
                accA[4*q+0] = fmaf(wA, c[q].x, accA[4*q+0]);
                accA[4*q+1] = fmaf(wA, c[q].y, accA[4*q+1]);
                accA[4*q+2] = fmaf(wA, c[q].z, accA[4*q+2]);
                accA[4*q+3] = fmaf(wA, c[q].w, accA[4*q+3]);
                accB[4*q+0] = fmaf(wB, c[q].x, accB[4*q+0]);
                accB[4*q+1] = fmaf(wB, c[q].y, accB[4*q+1]);
                accB[4*q+2] = fmaf(wB, c[q].z, accB[4*q+2]);
                accB[4*q+3] = fmaf(wB, c[q].w, accB[4*q+3]);
            }
            const float4* rc = (const float4*)(xs + (i + 2 < 28 ? i + 2 : 0) * 28);
            #pragma unroll
            for (int q = 0; q < 7; ++q) c[q] = rc[q];    // row for next even i
            float wA1 = Ws[p * 29 + i + 1];
            float wB1 = Ws[(p + 16) * 29 + i + 1];
            #pragma unroll
            for (int q = 0; q < 7; ++q) {
                accA[4*q+0] = fmaf(wA1, n[q].x, accA[4*q+0]);
                accA[4*q+1] = fmaf(wA1, n[q].y, accA[4*q+1]);
                accA[4*q+2] = fmaf(wA1, n[q].z, accA[4*q+2]);
                accA[4*q+3] = fmaf(wA1, n[q].w, accA[4*q+3]);
                accB[4*q+0] = fmaf(wB1, n[q].x, accB[4*q+0]);
                accB[4*q+1] = fmaf(wB1, n[q].y, accB[4*q+1]);
                accB[4*q+2] = fmaf(wB1, n[q].z, accB[4*q+2]);
                accB[4*q+3] = fmaf(wB1, n[q].w, accB[4*q+3]);
            }
        }

        // ---- sequential IF scan fused with layer 2 ----
        float v1a = 0.f, v1b = 0.f, v2 = 0.f, cnt = 0.f;
        #pragma unroll
        for (int t = 0; t < 28; ++t) {
            v1a += accA[t] + b1a;                  // neurons 0..15
            v1b += accB[t] + b1b;                  // neurons 16..31
            bool sA = (v1a >= 1.0f);
            bool sB = (v1b >= 1.0f);
            unsigned long long balA = __ballot(sA);
            unsigned long long balB = __ballot(sB);
            if (sA) v1a = 0.f;                     // hard reset
            if (sB) v1b = 0.f;
            unsigned mlo = (unsigned)(balA >> (g16 * 16)) & 0xFFFFu;
            unsigned mhi = (unsigned)(balB >> (g16 * 16)) & 0xFFFFu;
            unsigned m = mlo | (mhi << 16);        // bit i = spike of neuron i

            if (p < 10) {
                unsigned c0 =  m        & 255u;
                unsigned c1 = (m >> 8)  & 255u;
                unsigned c2 = (m >> 16) & 255u;
                unsigned c3 =  m >> 24;
                float a2 =  P[(        c0) * 10 + p];
                a2      +=  P[( 256u + c1) * 10 + p];
                a2      +=  P[( 512u + c2) * 10 + p];
                a2      +=  P[( 768u + c3) * 10 + p];
                v2 += a2 + b2o;
                if (v2 >= 1.0f) { cnt += 1.f; v2 = 0.f; }
            }
        }

        if (p < 10 && ok) {
            out[(size_t)samp * 10 + p] = cnt / 28.0f;
        }
    }
}

extern "C" void kernel_launch(void* const* d_in, const int* in_sizes, int n_in,
                              void* d_out, int out_size, void* d_ws, size_t ws_size,
                              hipStream_t stream) {
    const float* x  = (const float*)d_in[0];
    const float* W1 = (const float*)d_in[1];
    const float* b1 = (const float*)d_in[2];
    const float* W2 = (const float*)d_in[3];
    const float* b2 = (const float*)d_in[4];
    float* out = (float*)d_out;

    int B = in_sizes[0] / 784;                        // 65536
    int nIter = (B + GRID * SPB - 1) / (GRID * SPB);  // 6 for B=65536
    snn_if_kernel<<<GRID, THREADS, 0, stream>>>(x, W1, b1, W2, b2, out, B, nIter);
}